// Round 2
// baseline (3259.130 us; speedup 1.0000x reference)
//
#include <hip/hip_runtime.h>

// GAWADecoder on MI355X (gfx950). ALL float tensors are fp32 (ref is jnp.float32;
// round-1 NaN + threshold arithmetic proved _any_bf16=False).
// Algebra: len-1 softmax => attention output static per row; layer-0 input GEMM =
// static gword + char-projection lookup. Recurrent loop: persistent blocks,
// bf16 MFMA operands (converted in-register / pre-converted weights),
// fp32 accumulation and fp32 masters for h, biases, and all additive terms.

typedef __bf16 bf16;
typedef __attribute__((ext_vector_type(8))) __bf16 bf16x8;
typedef __attribute__((ext_vector_type(4))) __bf16 bf16x4;
typedef __attribute__((ext_vector_type(4))) float fx4;

#define MFMA16(a, b, c) __builtin_amdgcn_mfma_f32_16x16x32_bf16(a, b, c, 0, 0, 0)

__device__ __forceinline__ float sigm(float x) { return 1.0f / (1.0f + expf(-x)); }

// load 8 consecutive fp32, round to bf16x8 (MFMA operand)
__device__ __forceinline__ bf16x8 cvt8(const float* __restrict__ p) {
    float4 u = ((const float4*)p)[0];
    float4 v = ((const float4*)p)[1];
    bf16x8 r;
    r[0] = (bf16)u.x; r[1] = (bf16)u.y; r[2] = (bf16)u.z; r[3] = (bf16)u.w;
    r[4] = (bf16)v.x; r[5] = (bf16)v.y; r[6] = (bf16)v.z; r[7] = (bf16)v.w;
    return r;
}

// ---------------------------------------------------------------------------
// fp32 -> bf16 bulk convert (loop weights). n must be a multiple of 4.
// ---------------------------------------------------------------------------
__global__ void f2b(const float* __restrict__ s, bf16* __restrict__ d, int n) {
    int i = (blockIdx.x * 256 + threadIdx.x) * 4;
    if (i >= n) return;
    float4 v = *(const float4*)(s + i);
    bf16x4 o;
    o[0] = (bf16)v.x; o[1] = (bf16)v.y; o[2] = (bf16)v.z; o[3] = (bf16)v.w;
    *(bf16x4*)(d + i) = o;
}

// ---------------------------------------------------------------------------
// out[M,N] = act(A[M,K] @ W[N,K]^T + bias), all fp32 in global; bf16 MFMA inside.
// Block: 256 thr (4 waves), BM=32, BN=256 (wave w owns cols [w*64, w*64+64)).
// ---------------------------------------------------------------------------
__global__ __launch_bounds__(256, 4) void gemm_bt(
    const float* __restrict__ A, int lda,
    const float* __restrict__ W, int ldw,
    const float* __restrict__ bias,
    float* __restrict__ out, int ldo, int act_tanh, int K)
{
    const int tid  = threadIdx.x;
    const int wid  = tid >> 6;
    const int lane = tid & 63;
    const int quad = lane >> 4;
    const int l16  = lane & 15;
    const int m0   = blockIdx.x * 32;
    const int n0   = blockIdx.y * 256 + wid * 64;

    fx4 acc[4][2];
#pragma unroll
    for (int j = 0; j < 4; ++j) {
        acc[j][0] = fx4{0.f, 0.f, 0.f, 0.f};
        acc[j][1] = fx4{0.f, 0.f, 0.f, 0.f};
    }

    const float* a0p = A + (size_t)(m0 + l16) * lda + quad * 8;
    const float* a1p = A + (size_t)(m0 + 16 + l16) * lda + quad * 8;

    for (int k0 = 0; k0 < K; k0 += 32) {
        bf16x8 a0 = cvt8(a0p + k0);
        bf16x8 a1 = cvt8(a1p + k0);
#pragma unroll
        for (int j = 0; j < 4; ++j) {
            bf16x8 b = cvt8(W + (size_t)(n0 + j * 16 + l16) * ldw + k0 + quad * 8);
            acc[j][0] = MFMA16(a0, b, acc[j][0]);
            acc[j][1] = MFMA16(a1, b, acc[j][1]);
        }
    }

#pragma unroll
    for (int j = 0; j < 4; ++j) {
        int n = n0 + j * 16 + l16;
        float bv = bias ? bias[n] : 0.0f;
#pragma unroll
        for (int rt = 0; rt < 2; ++rt) {
#pragma unroll
            for (int r = 0; r < 4; ++r) {
                int m = m0 + rt * 16 + quad * 4 + r;
                float v = acc[j][rt][r] + bv;
                if (act_tanh) v = tanhf(v);
                out[(size_t)m * ldo + n] = v;
            }
        }
    }
}

// ---------------------------------------------------------------------------
// Persistent recurrent kernel. 128 blocks x 512 thr (8 waves), 32 batch rows
// per block, t=0..31 internally (rows independent => no grid sync).
// Wave w owns cols [w*32, w*32+32) of EACH 256-wide gate block => r/z/n for a
// hidden column land in the same lane's accumulators; fp32 h master lives in
// that lane's registers (same owner every step). LDS: bf16 h copies (MFMA A).
// ---------------------------------------------------------------------------
__global__ __launch_bounds__(512, 2) void decoder_loop(
    const int*   __restrict__ tgt,      // (4096,32)
    const float* __restrict__ h0i,      // (4096,256) tanh(eword proj)
    const float* __restrict__ gword,    // (4096,768) eword part of gi0 (+b_ih0)
    const float* __restrict__ cproj,    // (256,768)  char_emb @ w_ih0[:,:64]^T
    const float* __restrict__ basel,    // (4096,256) static logits addend
    const bf16*  __restrict__ w_hh0, const float* __restrict__ b_hh0,
    const bf16*  __restrict__ w_ih1, const float* __restrict__ b_ih1,
    const bf16*  __restrict__ w_hh1, const float* __restrict__ b_hh1,
    const bf16*  __restrict__ proj_w,   // bf16 copy
    float* __restrict__ out)            // (4096,32,256)
{
    __shared__ __align__(16) bf16 hb0[32][264];   // +8 pad
    __shared__ __align__(16) bf16 hb1[32][264];
    __shared__ int ids_s[32];

    const int tid  = threadIdx.x;
    const int wid  = tid >> 6;
    const int lane = tid & 63;
    const int quad = lane >> 4;
    const int l16  = lane & 15;
    const int row0 = blockIdx.x * 32;

    // fp32 hidden-state masters in registers (lane owns (lrow,col) pairs)
    float h0m[2][2][4], h1m[2][2][4];
#pragma unroll
    for (int i = 0; i < 2; ++i)
#pragma unroll
        for (int rt = 0; rt < 2; ++rt)
#pragma unroll
            for (int r = 0; r < 4; ++r) {
                int lrow = rt * 16 + quad * 4 + r;
                int col  = wid * 32 + i * 16 + l16;
                float v = h0i[(size_t)(row0 + lrow) * 256 + col];
                h0m[i][rt][r] = v; h1m[i][rt][r] = v;
                bf16 bv = (bf16)v;
                hb0[lrow][col] = bv; hb1[lrow][col] = bv;
            }

    float bh0[3][2], bi1[3][2], bh1[3][2];
#pragma unroll
    for (int g = 0; g < 3; ++g)
#pragma unroll
        for (int i = 0; i < 2; ++i) {
            int n = g * 256 + wid * 32 + i * 16 + l16;
            bh0[g][i] = b_hh0[n];
            bi1[g][i] = b_ih1[n];
            bh1[g][i] = b_hh1[n];
        }

    for (int t = 0; t < 32; ++t) {
        if (tid < 32)
            ids_s[tid] = (t == 0) ? 1 : tgt[(row0 + tid) * 32 + (t - 1)];
        __syncthreads();   // ids ready; hb0/hb1 (incl. init) visible

        // -------- layer 0: gh0 = h0 @ w_hh0^T --------
        fx4 g0[3][2][2];
#pragma unroll
        for (int g = 0; g < 3; ++g)
#pragma unroll
            for (int i = 0; i < 2; ++i) {
                g0[g][i][0] = fx4{0.f, 0.f, 0.f, 0.f};
                g0[g][i][1] = fx4{0.f, 0.f, 0.f, 0.f};
            }
        for (int k0 = 0; k0 < 256; k0 += 32) {
            bf16x8 a0 = *(const bf16x8*)&hb0[l16][k0 + quad * 8];
            bf16x8 a1 = *(const bf16x8*)&hb0[16 + l16][k0 + quad * 8];
#pragma unroll
            for (int g = 0; g < 3; ++g)
#pragma unroll
                for (int i = 0; i < 2; ++i) {
                    int n = g * 256 + wid * 32 + i * 16 + l16;
                    bf16x8 b = *(const bf16x8*)(w_hh0 + n * 256 + k0 + quad * 8);
                    g0[g][i][0] = MFMA16(a0, b, g0[g][i][0]);
                    g0[g][i][1] = MFMA16(a1, b, g0[g][i][1]);
                }
        }

        // -------- layer-0 gates (gi0 = cproj[id] + gword, both fp32) --------
#pragma unroll
        for (int i = 0; i < 2; ++i)
#pragma unroll
            for (int rt = 0; rt < 2; ++rt)
#pragma unroll
                for (int r = 0; r < 4; ++r) {
                    int lrow = rt * 16 + quad * 4 + r;
                    int babs = row0 + lrow;
                    int col  = wid * 32 + i * 16 + l16;
                    const float* cp = cproj + (size_t)ids_s[lrow] * 768;
                    const float* gw = gword + (size_t)babs * 768;
                    float gr = cp[col]       + gw[col]       + g0[0][i][rt][r] + bh0[0][i];
                    float gz = cp[256 + col] + gw[256 + col] + g0[1][i][rt][r] + bh0[1][i];
                    float gn = cp[512 + col] + gw[512 + col];
                    float rr = sigm(gr);
                    float zz = sigm(gz);
                    float nn = tanhf(gn + rr * (g0[2][i][rt][r] + bh0[2][i]));
                    h0m[i][rt][r] = (1.0f - zz) * nn + zz * h0m[i][rt][r];
                }
        __syncthreads();   // everyone done reading old hb0
#pragma unroll
        for (int i = 0; i < 2; ++i)
#pragma unroll
            for (int rt = 0; rt < 2; ++rt)
#pragma unroll
                for (int r = 0; r < 4; ++r) {
                    int lrow = rt * 16 + quad * 4 + r;
                    int col  = wid * 32 + i * 16 + l16;
                    hb0[lrow][col] = (bf16)h0m[i][rt][r];
                }
        __syncthreads();   // new h0 visible

        // -------- layer 1: gi1 = h0new @ w_ih1^T ; gh1 = h1 @ w_hh1^T --------
        fx4 gI[3][2][2], gH[3][2][2];
#pragma unroll
        for (int g = 0; g < 3; ++g)
#pragma unroll
            for (int i = 0; i < 2; ++i) {
                gI[g][i][0] = fx4{0.f, 0.f, 0.f, 0.f}; gI[g][i][1] = fx4{0.f, 0.f, 0.f, 0.f};
                gH[g][i][0] = fx4{0.f, 0.f, 0.f, 0.f}; gH[g][i][1] = fx4{0.f, 0.f, 0.f, 0.f};
            }
        for (int k0 = 0; k0 < 256; k0 += 32) {
            bf16x8 a0 = *(const bf16x8*)&hb0[l16][k0 + quad * 8];
            bf16x8 a1 = *(const bf16x8*)&hb0[16 + l16][k0 + quad * 8];
            bf16x8 c0 = *(const bf16x8*)&hb1[l16][k0 + quad * 8];
            bf16x8 c1 = *(const bf16x8*)&hb1[16 + l16][k0 + quad * 8];
#pragma unroll
            for (int g = 0; g < 3; ++g)
#pragma unroll
                for (int i = 0; i < 2; ++i) {
                    int n = g * 256 + wid * 32 + i * 16 + l16;
                    bf16x8 b1 = *(const bf16x8*)(w_ih1 + n * 256 + k0 + quad * 8);
                    gI[g][i][0] = MFMA16(a0, b1, gI[g][i][0]);
                    gI[g][i][1] = MFMA16(a1, b1, gI[g][i][1]);
                    bf16x8 b2 = *(const bf16x8*)(w_hh1 + n * 256 + k0 + quad * 8);
                    gH[g][i][0] = MFMA16(c0, b2, gH[g][i][0]);
                    gH[g][i][1] = MFMA16(c1, b2, gH[g][i][1]);
                }
        }

#pragma unroll
        for (int i = 0; i < 2; ++i)
#pragma unroll
            for (int rt = 0; rt < 2; ++rt)
#pragma unroll
                for (int r = 0; r < 4; ++r) {
                    float rr = sigm(gI[0][i][rt][r] + bi1[0][i] + gH[0][i][rt][r] + bh1[0][i]);
                    float zz = sigm(gI[1][i][rt][r] + bi1[1][i] + gH[1][i][rt][r] + bh1[1][i]);
                    float nn = tanhf(gI[2][i][rt][r] + bi1[2][i] + rr * (gH[2][i][rt][r] + bh1[2][i]));
                    h1m[i][rt][r] = (1.0f - zz) * nn + zz * h1m[i][rt][r];
                }
        __syncthreads();   // everyone done reading old hb1
#pragma unroll
        for (int i = 0; i < 2; ++i)
#pragma unroll
            for (int rt = 0; rt < 2; ++rt)
#pragma unroll
                for (int r = 0; r < 4; ++r) {
                    int lrow = rt * 16 + quad * 4 + r;
                    int col  = wid * 32 + i * 16 + l16;
                    hb1[lrow][col] = (bf16)h1m[i][rt][r];
                }
        __syncthreads();   // new h1 visible

        // -------- logits_t = h1 @ proj_w^T + base_logits --------
        fx4 gl[2][2];
#pragma unroll
        for (int i = 0; i < 2; ++i) {
            gl[i][0] = fx4{0.f, 0.f, 0.f, 0.f};
            gl[i][1] = fx4{0.f, 0.f, 0.f, 0.f};
        }
        for (int k0 = 0; k0 < 256; k0 += 32) {
            bf16x8 a0 = *(const bf16x8*)&hb1[l16][k0 + quad * 8];
            bf16x8 a1 = *(const bf16x8*)&hb1[16 + l16][k0 + quad * 8];
#pragma unroll
            for (int i = 0; i < 2; ++i) {
                int n = wid * 32 + i * 16 + l16;
                bf16x8 b = *(const bf16x8*)(proj_w + n * 256 + k0 + quad * 8);
                gl[i][0] = MFMA16(a0, b, gl[i][0]);
                gl[i][1] = MFMA16(a1, b, gl[i][1]);
            }
        }
#pragma unroll
        for (int i = 0; i < 2; ++i)
#pragma unroll
            for (int rt = 0; rt < 2; ++rt)
#pragma unroll
                for (int r = 0; r < 4; ++r) {
                    int lrow = rt * 16 + quad * 4 + r;
                    int babs = row0 + lrow;
                    int v    = wid * 32 + i * 16 + l16;
                    out[((size_t)babs * 32 + t) * 256 + v] = gl[i][rt][r] + basel[(size_t)babs * 256 + v];
                }
    }
}

// ---------------------------------------------------------------------------
extern "C" void kernel_launch(void* const* d_in, const int* in_sizes, int n_in,
                              void* d_out, int out_size, void* d_ws, size_t ws_size,
                              hipStream_t stream)
{
    const float* eword      = (const float*)d_in[0];
    const int*   tgt        = (const int*)  d_in[1];
    const float* char_emb   = (const float*)d_in[2];
    const float* ew_w       = (const float*)d_in[3];
    const float* ew_b       = (const float*)d_in[4];
    const float* w_ih0      = (const float*)d_in[5];   // (768, 832)
    const float* w_hh0      = (const float*)d_in[6];
    const float* b_ih0      = (const float*)d_in[7];
    const float* b_hh0      = (const float*)d_in[8];
    const float* w_ih1      = (const float*)d_in[9];
    const float* w_hh1      = (const float*)d_in[10];
    const float* b_ih1      = (const float*)d_in[11];
    const float* b_hh1      = (const float*)d_in[12];
    const float* attn_in_w  = (const float*)d_in[13];  // wq|wk|wv (q,k dead)
    const float* attn_in_b  = (const float*)d_in[14];
    const float* attn_out_w = (const float*)d_in[15];
    const float* attn_out_b = (const float*)d_in[16];
    // d_in[17..18] key_w/key_b dead (len-1 softmax)
    const float* val_w      = (const float*)d_in[19];
    const float* val_b      = (const float*)d_in[20];
    const float* proj_w     = (const float*)d_in[21];
    const float* proj_b     = (const float*)d_in[22];

    char* ws = (char*)d_ws;
    float* h0i   = (float*)ws;  ws += (size_t)4096 * 256 * 4;   //  4 MB
    float* gwrd  = (float*)ws;  ws += (size_t)4096 * 768 * 4;   // 12 MB
    float* cproj = (float*)ws;  ws += (size_t)256  * 768 * 4;   // .75 MB
    float* basel = (float*)ws;  ws += (size_t)4096 * 256 * 4;   //  4 MB
    float* buf1  = (float*)ws;  ws += (size_t)4096 * 256 * 4;   //  4 MB (t1, a2)
    float* buf2  = (float*)ws;  ws += (size_t)4096 * 256 * 4;   //  4 MB (ev)
    bf16*  wbhh0 = (bf16*)ws;   ws += (size_t)768 * 256 * 2;
    bf16*  wbih1 = (bf16*)ws;   ws += (size_t)768 * 256 * 2;
    bf16*  wbhh1 = (bf16*)ws;   ws += (size_t)768 * 256 * 2;
    bf16*  wbprj = (bf16*)ws;   ws += (size_t)256 * 256 * 2;    // ~30 MB total

    dim3 blk(256);
    // loop-weight bf16 copies
    f2b<<<dim3(192), blk, 0, stream>>>(w_hh0, wbhh0, 768 * 256);
    f2b<<<dim3(192), blk, 0, stream>>>(w_ih1, wbih1, 768 * 256);
    f2b<<<dim3(192), blk, 0, stream>>>(w_hh1, wbhh1, 768 * 256);
    f2b<<<dim3(64),  blk, 0, stream>>>(proj_w, wbprj, 256 * 256);

    // h0 = tanh(eword @ ew_w^T + ew_b)
    gemm_bt<<<dim3(128, 1), blk, 0, stream>>>(eword, 768, ew_w, 768, ew_b, h0i, 256, 1, 768);
    // gword = eword @ w_ih0[:,64:]^T + b_ih0
    gemm_bt<<<dim3(128, 3), blk, 0, stream>>>(eword, 768, w_ih0 + 64, 832, b_ih0, gwrd, 768, 0, 768);
    // cproj = char_emb @ w_ih0[:,:64]^T   (row PAD of char_emb is exactly 0)
    gemm_bt<<<dim3(8, 3),   blk, 0, stream>>>(char_emb, 64, w_ih0, 832, nullptr, cproj, 768, 0, 64);
    // t1 = eword @ val_w^T + val_b
    gemm_bt<<<dim3(128, 1), blk, 0, stream>>>(eword, 768, val_w, 768, val_b, buf1, 256, 0, 768);
    // ev = t1 @ wv^T + bv   (wv = attn_in_w rows 512..767)
    gemm_bt<<<dim3(128, 1), blk, 0, stream>>>(buf1, 256, attn_in_w + 512 * 256, 256, attn_in_b + 512, buf2, 256, 0, 256);
    // a2 = ev @ attn_out_w^T + attn_out_b   (static attention output)
    gemm_bt<<<dim3(128, 1), blk, 0, stream>>>(buf2, 256, attn_out_w, 256, attn_out_b, buf1, 256, 0, 256);
    // base_logits = a2 @ proj_w^T + proj_b
    gemm_bt<<<dim3(128, 1), blk, 0, stream>>>(buf1, 256, proj_w, 256, proj_b, basel, 256, 0, 256);

    // recurrent decode, logits fused in-loop
    decoder_loop<<<dim3(128), dim3(512), 0, stream>>>(
        tgt, h0i, gwrd, cproj, basel,
        wbhh0, b_hh0, wbih1, b_ih1, wbhh1, b_hh1, wbprj, (float*)d_out);
}

// Round 3
// 2074.912 us; speedup vs baseline: 1.5707x; 1.5707x over previous
//
#include <hip/hip_runtime.h>

// GAWADecoder on MI355X (gfx950). All tensors fp32 in global; bf16 MFMA inside.
// R2 post-mortem: decoder_loop was latency-bound (MfmaUtil 2.7%, occ 10%,
// FETCH 2.9GB = L2 thrash). R3: hoist step-invariant gword to registers, drop
// basel/logits from the loop (deferred batched logits GEMM with a2 fused),
// 1024-thr blocks (4 waves/SIMD). Loop now reads ONLY weights (L2-resident).

typedef __bf16 bf16;
typedef __attribute__((ext_vector_type(8))) __bf16 bf16x8;
typedef __attribute__((ext_vector_type(4))) __bf16 bf16x4;
typedef __attribute__((ext_vector_type(4))) float fx4;

#define MFMA16(a, b, c) __builtin_amdgcn_mfma_f32_16x16x32_bf16(a, b, c, 0, 0, 0)

__device__ __forceinline__ float sigm(float x) { return 1.0f / (1.0f + expf(-x)); }

// load 8 consecutive fp32, round to bf16x8 (MFMA operand)
__device__ __forceinline__ bf16x8 cvt8(const float* __restrict__ p) {
    float4 u = ((const float4*)p)[0];
    float4 v = ((const float4*)p)[1];
    bf16x8 r;
    r[0] = (bf16)u.x; r[1] = (bf16)u.y; r[2] = (bf16)u.z; r[3] = (bf16)u.w;
    r[4] = (bf16)v.x; r[5] = (bf16)v.y; r[6] = (bf16)v.z; r[7] = (bf16)v.w;
    return r;
}

// bf16x8 h + fp32[8] -> bf16x8 (logits A-fragment: h1 + attn_out)
__device__ __forceinline__ bf16x8 addcvt8(bf16x8 h, const float* __restrict__ p) {
    float4 u = ((const float4*)p)[0];
    float4 v = ((const float4*)p)[1];
    bf16x8 r;
    r[0] = (bf16)((float)h[0] + u.x); r[1] = (bf16)((float)h[1] + u.y);
    r[2] = (bf16)((float)h[2] + u.z); r[3] = (bf16)((float)h[3] + u.w);
    r[4] = (bf16)((float)h[4] + v.x); r[5] = (bf16)((float)h[5] + v.y);
    r[6] = (bf16)((float)h[6] + v.z); r[7] = (bf16)((float)h[7] + v.w);
    return r;
}

// ---------------------------------------------------------------------------
__global__ void f2b(const float* __restrict__ s, bf16* __restrict__ d, int n) {
    int i = (blockIdx.x * 256 + threadIdx.x) * 4;
    if (i >= n) return;
    float4 v = *(const float4*)(s + i);
    bf16x4 o;
    o[0] = (bf16)v.x; o[1] = (bf16)v.y; o[2] = (bf16)v.z; o[3] = (bf16)v.w;
    *(bf16x4*)(d + i) = o;
}

// ---------------------------------------------------------------------------
// out[M,N] = act(A[M,K] @ W[N,K]^T + bias), fp32 in global; bf16 MFMA inside.
// ---------------------------------------------------------------------------
__global__ __launch_bounds__(256, 4) void gemm_bt(
    const float* __restrict__ A, int lda,
    const float* __restrict__ W, int ldw,
    const float* __restrict__ bias,
    float* __restrict__ out, int ldo, int act_tanh, int K)
{
    const int tid  = threadIdx.x;
    const int wid  = tid >> 6;
    const int lane = tid & 63;
    const int quad = lane >> 4;
    const int l16  = lane & 15;
    const int m0   = blockIdx.x * 32;
    const int n0   = blockIdx.y * 256 + wid * 64;

    fx4 acc[4][2];
#pragma unroll
    for (int j = 0; j < 4; ++j) {
        acc[j][0] = fx4{0.f, 0.f, 0.f, 0.f};
        acc[j][1] = fx4{0.f, 0.f, 0.f, 0.f};
    }

    const float* a0p = A + (size_t)(m0 + l16) * lda + quad * 8;
    const float* a1p = A + (size_t)(m0 + 16 + l16) * lda + quad * 8;

    for (int k0 = 0; k0 < K; k0 += 32) {
        bf16x8 a0 = cvt8(a0p + k0);
        bf16x8 a1 = cvt8(a1p + k0);
#pragma unroll
        for (int j = 0; j < 4; ++j) {
            bf16x8 b = cvt8(W + (size_t)(n0 + j * 16 + l16) * ldw + k0 + quad * 8);
            acc[j][0] = MFMA16(a0, b, acc[j][0]);
            acc[j][1] = MFMA16(a1, b, acc[j][1]);
        }
    }

#pragma unroll
    for (int j = 0; j < 4; ++j) {
        int n = n0 + j * 16 + l16;
        float bv = bias ? bias[n] : 0.0f;
#pragma unroll
        for (int rt = 0; rt < 2; ++rt)
#pragma unroll
            for (int r = 0; r < 4; ++r) {
                int m = m0 + rt * 16 + quad * 4 + r;
                float v = acc[j][rt][r] + bv;
                if (act_tanh) v = tanhf(v);
                out[(size_t)m * ldo + n] = v;
            }
    }
}

// ---------------------------------------------------------------------------
// Persistent recurrent kernel. 128 blocks x 1024 thr (16 waves, 4 waves/SIMD),
// 32 batch rows/block, t=0..31 internally. Wave w owns cols [w*16, w*16+16)
// of each 256-wide gate block; r/z/n for a column land in one lane's accums.
// Step-invariant gword/biases/h-masters in registers; per-step global reads
// are ONLY the bf16 loop weights (1.18 MB/block, L2-resident) + cproj gather.
// Logits deferred: h1(t) stored bf16 to global, batched GEMM afterwards.
// ---------------------------------------------------------------------------
__global__ __launch_bounds__(1024) void decoder_loop(
    const int*   __restrict__ tgt,      // (4096,32)
    const float* __restrict__ h0i,      // (4096,256)
    const float* __restrict__ gword,    // (4096,768) eword part of gi0 (+b_ih0)
    const float* __restrict__ cproj,    // (256,768)  char_emb @ w_ih0[:,:64]^T
    const bf16*  __restrict__ w_hh0, const float* __restrict__ b_hh0,
    const bf16*  __restrict__ w_ih1, const float* __restrict__ b_ih1,
    const bf16*  __restrict__ w_hh1, const float* __restrict__ b_hh1,
    bf16* __restrict__ h1all)           // (4096,32,256) bf16
{
    __shared__ __align__(16) bf16 hb0[32][264];   // +8 pad
    __shared__ __align__(16) bf16 hb1[32][264];
    __shared__ int ids_s[32];

    const int tid  = threadIdx.x;
    const int wid  = tid >> 6;     // 0..15
    const int lane = tid & 63;
    const int quad = lane >> 4;
    const int l16  = lane & 15;
    const int row0 = blockIdx.x * 32;
    const int col  = wid * 16 + l16;

    // step-invariant per-lane state
    float h0m[2][4], h1m[2][4], gwv[3][2][4];
    float bh0[3], bi1[3], bh1[3];
#pragma unroll
    for (int g = 0; g < 3; ++g) {
        bh0[g] = b_hh0[g * 256 + col];
        bi1[g] = b_ih1[g * 256 + col];
        bh1[g] = b_hh1[g * 256 + col];
    }
#pragma unroll
    for (int rt = 0; rt < 2; ++rt)
#pragma unroll
        for (int r = 0; r < 4; ++r) {
            int lrow = rt * 16 + quad * 4 + r;
            float v = h0i[(size_t)(row0 + lrow) * 256 + col];
            h0m[rt][r] = v; h1m[rt][r] = v;
            bf16 bv = (bf16)v;
            hb0[lrow][col] = bv; hb1[lrow][col] = bv;
#pragma unroll
            for (int g = 0; g < 3; ++g)
                gwv[g][rt][r] = gword[(size_t)(row0 + lrow) * 768 + g * 256 + col];
        }

    for (int t = 0; t < 32; ++t) {
        if (tid < 32)
            ids_s[tid] = (t == 0) ? 1 : tgt[(row0 + tid) * 32 + (t - 1)];
        __syncthreads();   // ids ready; hb0/hb1 writes visible

        // cproj gather issued early, overlaps layer-0 GEMM
        float cpv[3][2][4];
#pragma unroll
        for (int rt = 0; rt < 2; ++rt)
#pragma unroll
            for (int r = 0; r < 4; ++r) {
                int id = ids_s[rt * 16 + quad * 4 + r];
#pragma unroll
                for (int g = 0; g < 3; ++g)
                    cpv[g][rt][r] = cproj[(size_t)id * 768 + g * 256 + col];
            }

        // -------- layer 0: gh0 = h0 @ w_hh0^T --------
        fx4 g0[3][2];
#pragma unroll
        for (int g = 0; g < 3; ++g) {
            g0[g][0] = fx4{0.f, 0.f, 0.f, 0.f};
            g0[g][1] = fx4{0.f, 0.f, 0.f, 0.f};
        }
        for (int k0 = 0; k0 < 256; k0 += 32) {
            bf16x8 a0 = *(const bf16x8*)&hb0[l16][k0 + quad * 8];
            bf16x8 a1 = *(const bf16x8*)&hb0[16 + l16][k0 + quad * 8];
#pragma unroll
            for (int g = 0; g < 3; ++g) {
                bf16x8 b = *(const bf16x8*)(w_hh0 + (size_t)(g * 256 + col) * 256 + k0 + quad * 8);
                g0[g][0] = MFMA16(a0, b, g0[g][0]);
                g0[g][1] = MFMA16(a1, b, g0[g][1]);
            }
        }

        // -------- layer-0 gates --------
#pragma unroll
        for (int rt = 0; rt < 2; ++rt)
#pragma unroll
            for (int r = 0; r < 4; ++r) {
                float gr = cpv[0][rt][r] + gwv[0][rt][r] + g0[0][rt][r] + bh0[0];
                float gz = cpv[1][rt][r] + gwv[1][rt][r] + g0[1][rt][r] + bh0[1];
                float gn = cpv[2][rt][r] + gwv[2][rt][r];
                float rr = sigm(gr);
                float zz = sigm(gz);
                float nn = tanhf(gn + rr * (g0[2][rt][r] + bh0[2]));
                h0m[rt][r] = (1.0f - zz) * nn + zz * h0m[rt][r];
            }
        __syncthreads();   // done reading old hb0
#pragma unroll
        for (int rt = 0; rt < 2; ++rt)
#pragma unroll
            for (int r = 0; r < 4; ++r)
                hb0[rt * 16 + quad * 4 + r][col] = (bf16)h0m[rt][r];
        __syncthreads();   // new h0 visible

        // -------- layer 1: gi1 = h0new @ w_ih1^T ; gh1 = h1 @ w_hh1^T --------
        fx4 gI[3][2], gH[3][2];
#pragma unroll
        for (int g = 0; g < 3; ++g) {
            gI[g][0] = fx4{0.f, 0.f, 0.f, 0.f}; gI[g][1] = fx4{0.f, 0.f, 0.f, 0.f};
            gH[g][0] = fx4{0.f, 0.f, 0.f, 0.f}; gH[g][1] = fx4{0.f, 0.f, 0.f, 0.f};
        }
        for (int k0 = 0; k0 < 256; k0 += 32) {
            bf16x8 a0 = *(const bf16x8*)&hb0[l16][k0 + quad * 8];
            bf16x8 a1 = *(const bf16x8*)&hb0[16 + l16][k0 + quad * 8];
            bf16x8 c0 = *(const bf16x8*)&hb1[l16][k0 + quad * 8];
            bf16x8 c1 = *(const bf16x8*)&hb1[16 + l16][k0 + quad * 8];
#pragma unroll
            for (int g = 0; g < 3; ++g) {
                bf16x8 b1 = *(const bf16x8*)(w_ih1 + (size_t)(g * 256 + col) * 256 + k0 + quad * 8);
                gI[g][0] = MFMA16(a0, b1, gI[g][0]);
                gI[g][1] = MFMA16(a1, b1, gI[g][1]);
                bf16x8 b2 = *(const bf16x8*)(w_hh1 + (size_t)(g * 256 + col) * 256 + k0 + quad * 8);
                gH[g][0] = MFMA16(c0, b2, gH[g][0]);
                gH[g][1] = MFMA16(c1, b2, gH[g][1]);
            }
        }

#pragma unroll
        for (int rt = 0; rt < 2; ++rt)
#pragma unroll
            for (int r = 0; r < 4; ++r) {
                float rr = sigm(gI[0][rt][r] + bi1[0] + gH[0][rt][r] + bh1[0]);
                float zz = sigm(gI[1][rt][r] + bi1[1] + gH[1][rt][r] + bh1[1]);
                float nn = tanhf(gI[2][rt][r] + bi1[2] + rr * (gH[2][rt][r] + bh1[2]));
                h1m[rt][r] = (1.0f - zz) * nn + zz * h1m[rt][r];
            }
        __syncthreads();   // done reading old hb1
#pragma unroll
        for (int rt = 0; rt < 2; ++rt)
#pragma unroll
            for (int r = 0; r < 4; ++r) {
                int lrow = rt * 16 + quad * 4 + r;
                bf16 hv = (bf16)h1m[rt][r];
                hb1[lrow][col] = hv;
                h1all[((size_t)(row0 + lrow) * 32 + t) * 256 + col] = hv;
            }
        __syncthreads();   // new h1 visible
    }
}

// ---------------------------------------------------------------------------
// Final logits: out[m,v] = (h1[m,:] + a2[m>>5,:]) @ pw^T + pb[v],  M=131072.
// 4096 blocks x 256 thr — massively parallel, HBM-streaming.
// ---------------------------------------------------------------------------
__global__ __launch_bounds__(256, 4) void logits_final(
    const bf16*  __restrict__ h1,    // (131072,256) bf16
    const float* __restrict__ a2,    // (4096,256) attn_out (fp32)
    const bf16*  __restrict__ pw,    // (256,256) bf16
    const float* __restrict__ pb,    // (256,)
    float* __restrict__ out)         // (131072,256)
{
    const int tid  = threadIdx.x;
    const int wid  = tid >> 6;
    const int lane = tid & 63;
    const int quad = lane >> 4;
    const int l16  = lane & 15;
    const int m0   = blockIdx.x * 32;
    const int n0   = wid * 64;
    const int b    = m0 >> 5;          // all 32 rows share one batch index

    fx4 acc[4][2];
#pragma unroll
    for (int j = 0; j < 4; ++j) {
        acc[j][0] = fx4{0.f, 0.f, 0.f, 0.f};
        acc[j][1] = fx4{0.f, 0.f, 0.f, 0.f};
    }

    for (int k0 = 0; k0 < 256; k0 += 32) {
        bf16x8 h0 = *(const bf16x8*)(h1 + (size_t)(m0 + l16) * 256 + k0 + quad * 8);
        bf16x8 h1v = *(const bf16x8*)(h1 + (size_t)(m0 + 16 + l16) * 256 + k0 + quad * 8);
        const float* ap = a2 + (size_t)b * 256 + k0 + quad * 8;
        bf16x8 a0 = addcvt8(h0, ap);
        bf16x8 a1 = addcvt8(h1v, ap);
#pragma unroll
        for (int j = 0; j < 4; ++j) {
            bf16x8 bb = *(const bf16x8*)(pw + (size_t)(n0 + j * 16 + l16) * 256 + k0 + quad * 8);
            acc[j][0] = MFMA16(a0, bb, acc[j][0]);
            acc[j][1] = MFMA16(a1, bb, acc[j][1]);
        }
    }

#pragma unroll
    for (int j = 0; j < 4; ++j) {
        int n = n0 + j * 16 + l16;
        float bv = pb[n];
#pragma unroll
        for (int rt = 0; rt < 2; ++rt)
#pragma unroll
            for (int r = 0; r < 4; ++r) {
                int m = m0 + rt * 16 + quad * 4 + r;
                out[(size_t)m * 256 + n] = acc[j][rt][r] + bv;
            }
    }
}

// ---------------------------------------------------------------------------
extern "C" void kernel_launch(void* const* d_in, const int* in_sizes, int n_in,
                              void* d_out, int out_size, void* d_ws, size_t ws_size,
                              hipStream_t stream)
{
    const float* eword      = (const float*)d_in[0];
    const int*   tgt        = (const int*)  d_in[1];
    const float* char_emb   = (const float*)d_in[2];
    const float* ew_w       = (const float*)d_in[3];
    const float* ew_b       = (const float*)d_in[4];
    const float* w_ih0      = (const float*)d_in[5];   // (768, 832)
    const float* w_hh0      = (const float*)d_in[6];
    const float* b_ih0      = (const float*)d_in[7];
    const float* b_hh0      = (const float*)d_in[8];
    const float* w_ih1      = (const float*)d_in[9];
    const float* w_hh1      = (const float*)d_in[10];
    const float* b_ih1      = (const float*)d_in[11];
    const float* b_hh1      = (const float*)d_in[12];
    const float* attn_in_w  = (const float*)d_in[13];  // wq|wk|wv (q,k dead)
    const float* attn_in_b  = (const float*)d_in[14];
    const float* attn_out_w = (const float*)d_in[15];
    const float* attn_out_b = (const float*)d_in[16];
    // d_in[17..18] key_w/key_b dead (len-1 softmax)
    const float* val_w      = (const float*)d_in[19];
    const float* val_b      = (const float*)d_in[20];
    const float* proj_w     = (const float*)d_in[21];
    const float* proj_b     = (const float*)d_in[22];

    char* ws = (char*)d_ws;
    float* h0i   = (float*)ws;  ws += (size_t)4096 * 256 * 4;   //  4 MB
    float* gwrd  = (float*)ws;  ws += (size_t)4096 * 768 * 4;   // 12 MB
    float* cproj = (float*)ws;  ws += (size_t)256  * 768 * 4;   // .75 MB
    float* a2    = (float*)ws;  ws += (size_t)4096 * 256 * 4;   //  4 MB
    float* buf1  = (float*)ws;  ws += (size_t)4096 * 256 * 4;   //  4 MB (t1)
    float* buf2  = (float*)ws;  ws += (size_t)4096 * 256 * 4;   //  4 MB (ev)
    bf16*  wbhh0 = (bf16*)ws;   ws += (size_t)768 * 256 * 2;
    bf16*  wbih1 = (bf16*)ws;   ws += (size_t)768 * 256 * 2;
    bf16*  wbhh1 = (bf16*)ws;   ws += (size_t)768 * 256 * 2;
    bf16*  wbprj = (bf16*)ws;   ws += (size_t)256 * 256 * 2;
    bf16*  h1all = (bf16*)ws;   ws += (size_t)4096 * 32 * 256 * 2;  // 67 MB (~97 MB total)

    dim3 blk(256);
    f2b<<<dim3(192), blk, 0, stream>>>(w_hh0, wbhh0, 768 * 256);
    f2b<<<dim3(192), blk, 0, stream>>>(w_ih1, wbih1, 768 * 256);
    f2b<<<dim3(192), blk, 0, stream>>>(w_hh1, wbhh1, 768 * 256);
    f2b<<<dim3(64),  blk, 0, stream>>>(proj_w, wbprj, 256 * 256);

    // h0 = tanh(eword @ ew_w^T + ew_b)
    gemm_bt<<<dim3(128, 1), blk, 0, stream>>>(eword, 768, ew_w, 768, ew_b, h0i, 256, 1, 768);
    // gword = eword @ w_ih0[:,64:]^T + b_ih0
    gemm_bt<<<dim3(128, 3), blk, 0, stream>>>(eword, 768, w_ih0 + 64, 832, b_ih0, gwrd, 768, 0, 768);
    // cproj = char_emb @ w_ih0[:,:64]^T   (PAD row of char_emb is zero)
    gemm_bt<<<dim3(8, 3),   blk, 0, stream>>>(char_emb, 64, w_ih0, 832, nullptr, cproj, 768, 0, 64);
    // attention chain (static): t1 = ew@vw^T+vb; ev = t1@wv^T+bv; a2 = ev@ao^T+ab
    gemm_bt<<<dim3(128, 1), blk, 0, stream>>>(eword, 768, val_w, 768, val_b, buf1, 256, 0, 768);
    gemm_bt<<<dim3(128, 1), blk, 0, stream>>>(buf1, 256, attn_in_w + 512 * 256, 256, attn_in_b + 512, buf2, 256, 0, 256);
    gemm_bt<<<dim3(128, 1), blk, 0, stream>>>(buf2, 256, attn_out_w, 256, attn_out_b, a2, 256, 0, 256);

    // recurrent decode (h1 trajectory to global)
    decoder_loop<<<dim3(128), dim3(1024), 0, stream>>>(
        tgt, h0i, gwrd, cproj,
        wbhh0, b_hh0, wbih1, b_ih1, wbhh1, b_hh1, h1all);

    // batched logits: out = (h1 + a2) @ pw^T + pb
    logits_final<<<dim3(4096), blk, 0, stream>>>(h1all, a2, wbprj, proj_b, (float*)d_out);
}